// Round 10
// baseline (207.881 us; speedup 1.0000x reference)
//
#include <hip/hip_runtime.h>
#include <math.h>

#define NUM 576
#define BSTR 50
#define CTH 512
// dynamic LDS: band (576*50) + CTH-float dummy sink
#define CHOL_LDS_BYTES ((NUM * BSTR + CTH) * sizeof(float))

__device__ __forceinline__ float leakyf(float v) { return v > 0.f ? v : 0.01f * v; }
__device__ __forceinline__ float sigmoidf(float v) { return 1.f / (1.f + __expf(-v)); }
__device__ __forceinline__ float rdlane(float v, int l) {
  return __uint_as_float(__builtin_amdgcn_readlane(__float_as_uint(v), l));
}

// ---------------------------------------------------------------------------
// conv1 + SE fused. Halo-padded LDS staging (26x26 per channel, zero halo).
// ---------------------------------------------------------------------------
__global__ __launch_bounds__(576) void conv1se_kernel(
    const float* __restrict__ x,
    const float* __restrict__ wa, const float* __restrict__ ba,
    const float* __restrict__ wg, const float* __restrict__ bg,
    const float* __restrict__ sw1, const float* __restrict__ sb1,
    const float* __restrict__ sw2, const float* __restrict__ sb2,
    float* __restrict__ outa, float* __restrict__ outg,
    float* __restrict__ sev, double* __restrict__ acc)
{
  __shared__ float sx[16 * 676];
  __shared__ float pooled[64];
  __shared__ float hid[32];
  const int co = blockIdx.x, n = blockIdx.y;
  const int tid = threadIdx.x;

  if (co == 64) {
    if (tid < 2) acc[n * 2 + tid] = 0.0;
    if (tid < 64) {
      const float4* xp4 = (const float4*)(x + (size_t)(n * 64 + tid) * 576);
      float s = 0.f;
      for (int p = 0; p < 144; ++p) {
        float4 v = xp4[p];
        s += v.x + v.y + v.z + v.w;
      }
      pooled[tid] = s * (1.f / 576.f);
    }
    __syncthreads();
    if (tid < 32) {
      float h = sb1[tid];
      for (int c = 0; c < 64; ++c) h += pooled[c] * sw1[tid * 64 + c];
      hid[tid] = leakyf(h);
    }
    __syncthreads();
    if (tid < 16) {
      float v = sb2[tid];
      for (int j = 0; j < 32; ++j) v += hid[j] * sw2[tid * 32 + j];
      sev[n * 16 + tid] = sigmoidf(v);
    }
    return;
  }

  const int py = tid / 24, px = tid - py * 24;
  const int hb0 = py * 26 + px;
  for (int i = tid; i < 16 * 676; i += 576) sx[i] = 0.f;
  float acc_a = ba[co];
  float acc_g = bg[co];
  for (int c0 = 0; c0 < 64; c0 += 16) {
    __syncthreads();
#pragma unroll
    for (int q = 0; q < 4; ++q) {
      const int p = tid + q * 576;
      const int k = p / 144;
      const int r = p - k * 144;
      const int pix = r * 4;
      const int ppy = pix / 24, ppx = pix - ppy * 24;
      const float4 v = *(const float4*)&x[(size_t)(n * 64 + c0) * 576 + p * 4];
      float* d = &sx[k * 676 + (ppy + 1) * 26 + ppx + 1];
      d[0] = v.x; d[1] = v.y; d[2] = v.z; d[3] = v.w;
    }
    __syncthreads();
#pragma unroll 4
    for (int k = 0; k < 16; ++k) {
      const float* wpa = wa + (co * 64 + c0 + k) * 9;
      const float* wpg = wg + (co * 64 + c0 + k) * 9;
      const float* sp = &sx[k * 676 + hb0];
#pragma unroll
      for (int dy = 0; dy < 3; ++dy)
#pragma unroll
        for (int dx = 0; dx < 3; ++dx) {
          const float v = sp[dy * 26 + dx];
          acc_a += v * wpa[dy * 3 + dx];
          acc_g += v * wpg[dy * 3 + dx];
        }
    }
  }
  const int o = (n * 64 + co) * 576 + tid;
  outa[o] = leakyf(acc_a);
  outg[o] = leakyf(acc_g);
}

// ---------------------------------------------------------------------------
// conv2: second 3x3 conv per branch (halo-padded staging).
// ---------------------------------------------------------------------------
__global__ __launch_bounds__(576) void conv2_kernel(
    const float* __restrict__ t1a, const float* __restrict__ t1g,
    const float* __restrict__ wa, const float* __restrict__ ba,
    const float* __restrict__ wg, const float* __restrict__ bg,
    float* __restrict__ att, float* __restrict__ grd)
{
  __shared__ float sx[16 * 676];
  const int co = blockIdx.x, n = blockIdx.y, br = blockIdx.z;
  const float* src = br ? t1g : t1a;
  const float* wp0 = br ? wg : wa;
  const float bias = br ? bg[co] : ba[co];
  float* dst = br ? grd : att;
  const int tid = threadIdx.x;
  const int py = tid / 24, px = tid - py * 24;
  const int hb0 = py * 26 + px;
  for (int i = tid; i < 16 * 676; i += 576) sx[i] = 0.f;
  float acc = bias;
  for (int c0 = 0; c0 < 64; c0 += 16) {
    __syncthreads();
#pragma unroll
    for (int q = 0; q < 4; ++q) {
      const int p = tid + q * 576;
      const int k = p / 144;
      const int r = p - k * 144;
      const int pix = r * 4;
      const int ppy = pix / 24, ppx = pix - ppy * 24;
      const float4 v = *(const float4*)&src[(size_t)(n * 64 + c0) * 576 + p * 4];
      float* d = &sx[k * 676 + (ppy + 1) * 26 + ppx + 1];
      d[0] = v.x; d[1] = v.y; d[2] = v.z; d[3] = v.w;
    }
    __syncthreads();
#pragma unroll 4
    for (int k = 0; k < 16; ++k) {
      const float* wp = wp0 + (co * 64 + c0 + k) * 9;
      const float* sp = &sx[k * 676 + hb0];
#pragma unroll
      for (int dy = 0; dy < 3; ++dy)
#pragma unroll
        for (int dx = 0; dx < 3; ++dx)
          acc += sp[dy * 26 + dx] * wp[dy * 3 + dx];
    }
  }
  if (br == 0) acc = sigmoidf(acc);
  dst[(n * 64 + co) * 576 + tid] = acc;
}

// ---------------------------------------------------------------------------
// back-substitution helpers (register double-buffered L/rd/tail prefetch)
// ---------------------------------------------------------------------------
#define BS_LOAD(ip, L, rr, tl)                                                \
  {                                                                           \
    _Pragma("unroll")                                                         \
    for (int a = 0; a < 8; ++a)                                               \
      _Pragma("unroll")                                                       \
      for (int bb = a + 1; bb < 8; ++bb)                                      \
        L[a][bb] = S[((ip) - a) * BSTR + (bb - a)];                           \
    _Pragma("unroll")                                                         \
    for (int k = 0; k < 8; ++k) rr[k] = RD_s[(ip) - k];                       \
    _Pragma("unroll")                                                         \
    for (int k = 0; k < 8; ++k) {                                             \
      const int d = 8 + t - k;                                                \
      tl[k] = (d <= 48) ? S[((ip) - k) * BSTR + d] : 0.f;                     \
    }                                                                         \
  }

#define BS_STEP(i, L, rr, tl, ipre, Lp, rrp, tlp)                             \
  {                                                                           \
    asm volatile("s_waitcnt lgkmcnt(0)" ::: "memory");                        \
    float zz[8];                                                              \
    _Pragma("unroll")                                                         \
    for (int k = 0; k < 8; ++k) zz[k] = RHS_s[(i) - k];                       \
    const int rb = (i) - 8 - t;                                               \
    const bool bok = rb >= 0;                                                 \
    const float zbv = RHS_s[bok ? rb : 0];                                    \
    if ((ipre) >= 7) BS_LOAD(ipre, Lp, rrp, tlp);                             \
    float xx[8];                                                              \
    xx[0] = zz[0] * rr[0];                                                    \
    _Pragma("unroll")                                                         \
    for (int k = 1; k < 8; ++k) {                                             \
      float a2 = zz[k];                                                       \
      _Pragma("unroll")                                                       \
      for (int m = 0; m < 8; ++m)                                             \
        if (m < k) a2 -= L[m][k] * xx[m];                                     \
      xx[k] = a2 * rr[k];                                                     \
    }                                                                         \
    float at = 0.f;                                                           \
    _Pragma("unroll")                                                         \
    for (int k = 0; k < 8; ++k) at += tl[k] * xx[k];                          \
    float* rp = bok ? &RHS_s[rb] : &DUMW[t];                                  \
    *rp = zbv - at;                                                           \
    float xv = xx[0];                                                         \
    _Pragma("unroll")                                                         \
    for (int k = 1; k < 8; ++k) xv = (t == k) ? xx[k] : xv;                   \
    if (t < 8) XS_s[(i) - t] = xv;                                            \
  }

// ---------------------------------------------------------------------------
// Fused banded Cholesky solver. 512 threads (8 waves) per system b = n*16+g.
// Rank-16 supersteps (36):
//  - target-value PREFETCH: each thread reads its 4 trailing-update targets
//    (band cols >= j+16, untouched by scale(j)) BEFORE the scale barrier, so
//    the RMW read latency hides under the serial chain.
//  - scale: wave-0 in-register 16-column micro-Cholesky, readlane broadcasts,
//    y-forward-substitution fused inline (uniform yac accumulators).
//  - update: 300 2x2 tiles (one per thread), CP[16][64] panel reads, write
//    prefetched-minus-sum back. Tile (16,16) seeds RD_s[j+16].
// Back substitution: 72 rank-8 steps with register-prefetched L blocks.
// ---------------------------------------------------------------------------
__global__ __launch_bounds__(CTH, 1) void chol_kernel(
    const float* __restrict__ att, const float* __restrict__ grd,
    float* __restrict__ sol, double* __restrict__ acc)
{
  extern __shared__ float S[];          // [28800] band + [CTH] dummy sink
  __shared__ float RHS_s[NUM];
  __shared__ float RD_s[NUM];
  __shared__ float XS_s[NUM];
  __shared__ __align__(16) float CP[16][64];
  __shared__ float DUMW[64];
  __shared__ double RW[16];
  const int b = blockIdx.x, tid = threadIdx.x;
  const int n = b >> 4, g = b & 15;
  const float* ac = att + (size_t)(n * 64 + g * 4) * 576;
  const float* gc = grd + (size_t)(n * 64 + g * 4) * 576;

  // --- 2x2 tile decode: (U,W), 0<=W<=U<=23, T = U(U+1)/2+W; r = 16+2*.
  int r1A, r2A;
  const bool okT = tid < 300;
  {
    const int T = okT ? tid : 0;
    int U = (int)((sqrtf(8.f * (float)T + 1.f) - 1.f) * 0.5f);
    while (U * (U + 1) / 2 > T) --U;
    while ((U + 1) * (U + 2) / 2 <= T) ++U;
    const int W = T - U * (U + 1) / 2;
    r1A = 16 + 2 * U; r2A = 16 + 2 * W;
  }

  // --- zero band
  for (int i = tid; i < NUM * BSTR; i += CTH) S[i] = 0.f;
  __syncthreads();

  // --- assemble band + rhs (verified math), seed rd[0]
  for (int i = tid; i < NUM; i += CTH) {
    float diag = 1e-12f, rv = 0.f;
    float od1 = 0.f, od2 = 0.f, od24 = 0.f, od48 = 0.f;
    if (((i + 1) % 24 != 0) && (i + 1 < NUM)) {
      float a0 = ac[0 * 576 + i]; float s = a0 * a0;
      diag += s; rv += s * gc[0 * 576 + i];
    }
    if (i - 1 >= 0 && (i % 24 != 0)) {
      float a0 = ac[0 * 576 + (i - 1)]; float s = a0 * a0;
      diag += s; rv -= s * gc[0 * 576 + (i - 1)]; od1 = -s;
    }
    if (i + 24 < NUM) {
      float a1 = ac[1 * 576 + i]; float s = a1 * a1;
      diag += s; rv += s * gc[1 * 576 + i];
    }
    if (i - 24 >= 0) {
      float a1 = ac[1 * 576 + (i - 24)]; float s = a1 * a1;
      diag += s; rv -= s * gc[1 * 576 + (i - 24)]; od24 = -s;
    }
    if (((i + 2) % 24 != 0) && (i + 2 < NUM)) {
      float a2 = ac[2 * 576 + i]; float s = a2 * a2;
      diag += s; rv += s * gc[2 * 576 + i];
    }
    if (i - 2 >= 0 && (i % 24 != 0)) {
      float a2 = ac[2 * 576 + (i - 2)]; float s = a2 * a2;
      diag += s; rv -= s * gc[2 * 576 + (i - 2)]; od2 = -s;
    }
    if (i + 48 < NUM) {
      float a3 = ac[3 * 576 + i]; float s = a3 * a3;
      diag += s; rv += s * gc[3 * 576 + i];
    }
    if (i - 48 >= 0) {
      float a3 = ac[3 * 576 + (i - 48)]; float s = a3 * a3;
      diag += s; rv -= s * gc[3 * 576 + (i - 48)]; od48 = -s;
    }
    if (i == NUM - 1) {
#pragma unroll
      for (int t = 0; t < 4; ++t) {
        float a = ac[t * 576 + (NUM - 1)]; float s = a * a;
        diag += s; rv += s * gc[t * 576 + (NUM - 1)];
      }
    }
    S[i * BSTR + 0] = diag;
    S[i * BSTR + 1] = od1;
    S[i * BSTR + 2] = od2;
    S[i * BSTR + 24] = od24;
    S[i * BSTR + 48] = od48;
    RHS_s[i] = rv;
    if (i == 0) RD_s[0] = rsqrtf(diag);
  }
  __syncthreads();

  // --- factorization: 36 rank-16 supersteps
  for (int j = 0; j < NUM; j += 16) {
    const int R = (NUM - 1) - j;
    // ---- target prefetch (cols >= j+16: disjoint from scale(j) writes)
    const bool a0 = okT && (r1A <= R);
    const bool a1 = okT && (r1A + 1 <= R);
    const int p00 = j * BSTR + 51 * r1A - r2A;
    float* q00 = a0 ? &S[p00] : &S[NUM * BSTR + tid];
    float* q01 = a0 ? &S[p00 - 1] : &S[NUM * BSTR + tid];
    float* q10 = a1 ? &S[p00 + 51] : &S[NUM * BSTR + tid];
    float* q11 = a1 ? &S[p00 + 50] : &S[NUM * BSTR + tid];
    const float pv00 = *q00, pv01 = *q01, pv10 = *q10, pv11 = *q11;
    // ---- scale phase: wave 0, in-register 16-col micro-Cholesky
    if (tid < 64) {
      const int t = tid;
      const int row = j + t;
      const bool rok = row < NUM;
      float v[16];
#pragma unroll
      for (int c = 0; c < 16; ++c) {
        const bool okc = rok && (t >= c) && (t - c <= 48);
        const int addr = okc ? (row * BSTR + (t - c)) : (NUM * BSTR + t);
        float vv = S[addr];
        v[c] = okc ? vv : 0.f;
      }
      float zb[16];
#pragma unroll
      for (int k = 0; k < 16; ++k) zb[k] = RHS_s[j + k];
      float z = RHS_s[rok ? row : j];
      z = rok ? z : 0.f;
      float rdv[16], y[16], yac[16];
#pragma unroll
      for (int k = 0; k < 16; ++k) yac[k] = 0.f;
#pragma unroll
      for (int k = 0; k < 16; ++k) {
        if (k == 0) {
          rdv[0] = RD_s[j];
        } else {
          rdv[k] = rsqrtf(rdlane(v[k], k));
        }
        v[k] *= rdv[k];
        y[k] = (zb[k] - yac[k]) * rdv[k];
#pragma unroll
        for (int m = k + 1; m < 16; ++m) {
          const float lp = rdlane(v[k], m);
          v[m] -= v[k] * lp;
          yac[m] += lp * y[k];
        }
        z -= v[k] * y[k];
      }
      // stores: scaled columns to band + CP panel
#pragma unroll
      for (int c = 0; c < 16; ++c) {
        const bool okc = rok && (t > c) && (t - c <= 48);
        float* bp = okc ? &S[row * BSTR + (t - c)] : &S[NUM * BSTR + t];
        *bp = v[c];
        CP[c][t] = okc ? v[c] : 0.f;
      }
      if (t < 16) {
        float yv = y[0], rv = rdv[0];
#pragma unroll
        for (int k = 1; k < 16; ++k) {
          yv = (t == k) ? y[k] : yv;
          rv = (t == k) ? rdv[k] : rv;
        }
        RHS_s[row] = yv;
        RD_s[row] = rv;
      } else {
        float* rp = rok ? &RHS_s[row] : &DUMW[t & 63];
        *rp = z;
      }
    }
    __syncthreads();
    // ---- rank-16 trailing update: one 2x2 tile per thread
    {
      float2 cr[16], cc[16];
#pragma unroll
      for (int c = 0; c < 16; ++c) {
        cr[c] = *(const float2*)&CP[c][r1A];
        cc[c] = *(const float2*)&CP[c][r2A];
      }
      float s00 = 0.f, s01 = 0.f, s10 = 0.f, s11 = 0.f;
#pragma unroll
      for (int c = 0; c < 16; ++c) {
        s00 += cr[c].x * cc[c].x; s01 += cr[c].x * cc[c].y;
        s10 += cr[c].y * cc[c].x; s11 += cr[c].y * cc[c].y;
      }
      const float t00 = pv00 - s00;
      *q00 = t00; *q01 = pv01 - s01;
      *q10 = pv10 - s10; *q11 = pv11 - s11;
      if (tid == 0 && a0)                  // tile (16,16): d_{j+16} final
        RD_s[j + 16] = rsqrtf(t00);
    }
    __syncthreads();
  }

  // --- back substitution: 72 rank-8 steps, single wave, reg-prefetched L
  if (tid < 64) {
    const int t = tid;
    float LA[8][8], LB[8][8], rrA[8], rrB[8], tlA[8], tlB[8];
    BS_LOAD(NUM - 1, LA, rrA, tlA);
    for (int i = NUM - 1; i >= 15; i -= 16) {
      BS_STEP(i, LA, rrA, tlA, i - 8, LB, rrB, tlB);
      BS_STEP(i - 8, LB, rrB, tlB, i - 16, LA, rrA, tlA);
    }
  }
  __syncthreads();

  // --- write solution + accumulate GroupNorm stats (double)
  double ls = 0.0, ls2 = 0.0;
  for (int i = tid; i < NUM; i += CTH) {
    const float xv = XS_s[i];
    sol[(size_t)b * NUM + i] = xv;
    ls += (double)xv;
    ls2 += (double)xv * (double)xv;
  }
#pragma unroll
  for (int off = 32; off > 0; off >>= 1) {
    ls += __shfl_down(ls, off);
    ls2 += __shfl_down(ls2, off);
  }
  if ((tid & 63) == 0) {
    RW[(tid >> 6) * 2] = ls;
    RW[(tid >> 6) * 2 + 1] = ls2;
  }
  __syncthreads();
  if (tid == 0) {
    double s = 0.0, s2 = 0.0;
#pragma unroll
    for (int wv = 0; wv < 8; ++wv) { s += RW[wv * 2]; s2 += RW[wv * 2 + 1]; }
    atomicAdd(&acc[n * 2], s);
    atomicAdd(&acc[n * 2 + 1], s2);
  }
}

// ---------------------------------------------------------------------------
// post conv fused with GroupNorm-apply + SE scale (halo-padded staging).
// ---------------------------------------------------------------------------
__global__ __launch_bounds__(576) void postgn_kernel(
    const float* __restrict__ sol, const double* __restrict__ acc,
    const float* __restrict__ sev,
    const float* __restrict__ gnw, const float* __restrict__ gnb,
    const float* __restrict__ w, const float* __restrict__ bias,
    float* __restrict__ out)
{
  __shared__ float sy[16 * 676];
  const int co = blockIdx.x, n = blockIdx.y, tid = threadIdx.x;
  const double mu_d = acc[n * 2] * (1.0 / 9216.0);
  const double var_d = acc[n * 2 + 1] * (1.0 / 9216.0) - mu_d * mu_d;
  const float rstd = (float)(1.0 / sqrt(var_d + 1e-5));
  const float muf = (float)mu_d;
  for (int i = tid; i < 16 * 676; i += 576) sy[i] = 0.f;
  __syncthreads();
#pragma unroll
  for (int q = 0; q < 4; ++q) {
    const int p = tid + q * 576;
    const int k = p / 144;
    const int r = p - k * 144;
    const int pix = r * 4;
    const int ppy = pix / 24, ppx = pix - ppy * 24;
    const float sv = sev[n * 16 + k];
    const float gw = gnw[k] * rstd;
    const float A = gw * sv;
    const float B = (gnb[k] - muf * gw) * sv;
    const float4 v = *(const float4*)&sol[(size_t)n * 9216 + p * 4];
    float* d = &sy[k * 676 + (ppy + 1) * 26 + ppx + 1];
    d[0] = v.x * A + B; d[1] = v.y * A + B;
    d[2] = v.z * A + B; d[3] = v.w * A + B;
  }
  __syncthreads();
  const int py = tid / 24, px = tid - py * 24;
  const int hb0 = py * 26 + px;
  float a = bias[co];
#pragma unroll 4
  for (int k = 0; k < 16; ++k) {
    const float* wp = w + (co * 16 + k) * 9;
    const float* sp = &sy[k * 676 + hb0];
#pragma unroll
    for (int dy = 0; dy < 3; ++dy)
#pragma unroll
      for (int dx = 0; dx < 3; ++dx)
        a += sp[dy * 26 + dx] * wp[dy * 3 + dx];
  }
  out[(size_t)(n * 128 + co) * 576 + tid] = a;
}

// ---------------------------------------------------------------------------
extern "C" void kernel_launch(void* const* d_in, const int* in_sizes, int n_in,
                              void* d_out, int out_size, void* d_ws, size_t ws_size,
                              hipStream_t stream) {
  const float* x       = (const float*)d_in[0];
  const float* grad_w1 = (const float*)d_in[2];
  const float* grad_b1 = (const float*)d_in[3];
  const float* grad_w2 = (const float*)d_in[4];
  const float* grad_b2 = (const float*)d_in[5];
  const float* att_w1  = (const float*)d_in[6];
  const float* att_b1  = (const float*)d_in[7];
  const float* att_w2  = (const float*)d_in[8];
  const float* att_b2  = (const float*)d_in[9];
  const float* se_w1   = (const float*)d_in[10];
  const float* se_b1   = (const float*)d_in[11];
  const float* se_w2   = (const float*)d_in[12];
  const float* se_b2   = (const float*)d_in[13];
  const float* gn_w    = (const float*)d_in[14];
  const float* gn_b    = (const float*)d_in[15];
  const float* post_w  = (const float*)d_in[16];
  const float* post_b  = (const float*)d_in[17];
  float* out = (float*)d_out;

  float* ws  = (float*)d_ws;
  float* t1a = ws;              // 147456
  float* t1g = t1a + 147456;    // 147456
  float* att = t1g + 147456;    // 147456
  float* grd = att + 147456;    // 147456
  float* sev = grd + 147456;    // 64
  float* sol = sev + 64;        // 36864
  double* acc = (double*)(sol + 36864);  // 8 doubles

  (void)hipFuncSetAttribute((const void*)chol_kernel,
                            hipFuncAttributeMaxDynamicSharedMemorySize,
                            (int)CHOL_LDS_BYTES);

  conv1se_kernel<<<dim3(65, 4), 576, 0, stream>>>(
      x, att_w1, att_b1, grad_w1, grad_b1,
      se_w1, se_b1, se_w2, se_b2, t1a, t1g, sev, acc);
  conv2_kernel<<<dim3(64, 4, 2), 576, 0, stream>>>(t1a, t1g, att_w2, att_b2,
                                                   grad_w2, grad_b2, att, grd);
  chol_kernel<<<64, CTH, CHOL_LDS_BYTES, stream>>>(att, grd, sol, acc);
  postgn_kernel<<<dim3(128, 4), 576, 0, stream>>>(sol, acc, sev, gn_w, gn_b,
                                                  post_w, post_b, out);
}

// Round 12
// 172.015 us; speedup vs baseline: 1.2085x; 1.2085x over previous
//
#include <hip/hip_runtime.h>
#include <math.h>

#define NUM 576
#define BSTR 50
#define CTH 512
// dynamic LDS: band (576*50) + CTH-float dummy sink
#define CHOL_LDS_BYTES ((NUM * BSTR + CTH) * sizeof(float))

__device__ __forceinline__ float leakyf(float v) { return v > 0.f ? v : 0.01f * v; }
__device__ __forceinline__ float sigmoidf(float v) { return 1.f / (1.f + __expf(-v)); }
__device__ __forceinline__ float rdlane(float v, int l) {
  return __uint_as_float(__builtin_amdgcn_readlane(__float_as_uint(v), l));
}

// ---------------------------------------------------------------------------
// conv1 + SE fused (halo-padded staging).
// ---------------------------------------------------------------------------
__global__ __launch_bounds__(576) void conv1se_kernel(
    const float* __restrict__ x,
    const float* __restrict__ wa, const float* __restrict__ ba,
    const float* __restrict__ wg, const float* __restrict__ bg,
    const float* __restrict__ sw1, const float* __restrict__ sb1,
    const float* __restrict__ sw2, const float* __restrict__ sb2,
    float* __restrict__ outa, float* __restrict__ outg,
    float* __restrict__ sev, double* __restrict__ acc)
{
  __shared__ float sx[16 * 676];
  __shared__ float pooled[64];
  __shared__ float hid[32];
  const int co = blockIdx.x, n = blockIdx.y;
  const int tid = threadIdx.x;

  if (co == 64) {
    if (tid < 2) acc[n * 2 + tid] = 0.0;
    if (tid < 64) {
      const float4* xp4 = (const float4*)(x + (size_t)(n * 64 + tid) * 576);
      float s = 0.f;
      for (int p = 0; p < 144; ++p) {
        float4 v = xp4[p];
        s += v.x + v.y + v.z + v.w;
      }
      pooled[tid] = s * (1.f / 576.f);
    }
    __syncthreads();
    if (tid < 32) {
      float h = sb1[tid];
      for (int c = 0; c < 64; ++c) h += pooled[c] * sw1[tid * 64 + c];
      hid[tid] = leakyf(h);
    }
    __syncthreads();
    if (tid < 16) {
      float v = sb2[tid];
      for (int j = 0; j < 32; ++j) v += hid[j] * sw2[tid * 32 + j];
      sev[n * 16 + tid] = sigmoidf(v);
    }
    return;
  }

  const int py = tid / 24, px = tid - py * 24;
  const int hb0 = py * 26 + px;
  for (int i = tid; i < 16 * 676; i += 576) sx[i] = 0.f;
  float acc_a = ba[co];
  float acc_g = bg[co];
  for (int c0 = 0; c0 < 64; c0 += 16) {
    __syncthreads();
#pragma unroll
    for (int q = 0; q < 4; ++q) {
      const int p = tid + q * 576;
      const int k = p / 144;
      const int r = p - k * 144;
      const int pix = r * 4;
      const int ppy = pix / 24, ppx = pix - ppy * 24;
      const float4 v = *(const float4*)&x[(size_t)(n * 64 + c0) * 576 + p * 4];
      float* d = &sx[k * 676 + (ppy + 1) * 26 + ppx + 1];
      d[0] = v.x; d[1] = v.y; d[2] = v.z; d[3] = v.w;
    }
    __syncthreads();
#pragma unroll 4
    for (int k = 0; k < 16; ++k) {
      const float* wpa = wa + (co * 64 + c0 + k) * 9;
      const float* wpg = wg + (co * 64 + c0 + k) * 9;
      const float* sp = &sx[k * 676 + hb0];
#pragma unroll
      for (int dy = 0; dy < 3; ++dy)
#pragma unroll
        for (int dx = 0; dx < 3; ++dx) {
          const float v = sp[dy * 26 + dx];
          acc_a += v * wpa[dy * 3 + dx];
          acc_g += v * wpg[dy * 3 + dx];
        }
    }
  }
  const int o = (n * 64 + co) * 576 + tid;
  outa[o] = leakyf(acc_a);
  outg[o] = leakyf(acc_g);
}

// ---------------------------------------------------------------------------
// conv2 (halo-padded staging).
// ---------------------------------------------------------------------------
__global__ __launch_bounds__(576) void conv2_kernel(
    const float* __restrict__ t1a, const float* __restrict__ t1g,
    const float* __restrict__ wa, const float* __restrict__ ba,
    const float* __restrict__ wg, const float* __restrict__ bg,
    float* __restrict__ att, float* __restrict__ grd)
{
  __shared__ float sx[16 * 676];
  const int co = blockIdx.x, n = blockIdx.y, br = blockIdx.z;
  const float* src = br ? t1g : t1a;
  const float* wp0 = br ? wg : wa;
  const float bias = br ? bg[co] : ba[co];
  float* dst = br ? grd : att;
  const int tid = threadIdx.x;
  const int py = tid / 24, px = tid - py * 24;
  const int hb0 = py * 26 + px;
  for (int i = tid; i < 16 * 676; i += 576) sx[i] = 0.f;
  float acc = bias;
  for (int c0 = 0; c0 < 64; c0 += 16) {
    __syncthreads();
#pragma unroll
    for (int q = 0; q < 4; ++q) {
      const int p = tid + q * 576;
      const int k = p / 144;
      const int r = p - k * 144;
      const int pix = r * 4;
      const int ppy = pix / 24, ppx = pix - ppy * 24;
      const float4 v = *(const float4*)&src[(size_t)(n * 64 + c0) * 576 + p * 4];
      float* d = &sx[k * 676 + (ppy + 1) * 26 + ppx + 1];
      d[0] = v.x; d[1] = v.y; d[2] = v.z; d[3] = v.w;
    }
    __syncthreads();
#pragma unroll 4
    for (int k = 0; k < 16; ++k) {
      const float* wp = wp0 + (co * 64 + c0 + k) * 9;
      const float* sp = &sx[k * 676 + hb0];
#pragma unroll
      for (int dy = 0; dy < 3; ++dy)
#pragma unroll
        for (int dx = 0; dx < 3; ++dx)
          acc += sp[dy * 26 + dx] * wp[dy * 3 + dx];
    }
  }
  if (br == 0) acc = sigmoidf(acc);
  dst[(n * 64 + co) * 576 + tid] = acc;
}

// ---------------------------------------------------------------------------
// forward/middle panel scale: in-register 8-col micro-Cholesky + fused z-sub.
// maxrow clips both L-stores and RHS writes (287 fwd / 335 middle).
// ---------------------------------------------------------------------------
__device__ __forceinline__ void scale_panel_f(
    float* __restrict__ S, float* RHS_s, float* RD_s, float (*CP)[64],
    float* DUMW, int t, int j, int maxrow, int dumidx)
{
  const int row = j + t;
  const bool rok = row <= maxrow;
  float v[8];
#pragma unroll
  for (int c = 0; c < 8; ++c) {
    const bool okc = rok && (t >= c) && (t - c <= 48);
    const int addr = okc ? (row * BSTR + (t - c)) : dumidx;
    float vv = S[addr];
    v[c] = okc ? vv : 0.f;
  }
  float zb[8];
#pragma unroll
  for (int k = 0; k < 8; ++k) zb[k] = RHS_s[j + k];
  float z = RHS_s[rok ? row : j];
  z = rok ? z : 0.f;
  float rdv[8], y[8], lp[8][8];
#pragma unroll
  for (int k = 0; k < 8; ++k) {
    if (k == 0) rdv[0] = RD_s[j];
    else rdv[k] = rsqrtf(rdlane(v[k], k));
    v[k] *= rdv[k];
#pragma unroll
    for (int m = k + 1; m < 8; ++m) {
      lp[m][k] = rdlane(v[k], m);
      v[m] -= v[k] * lp[m][k];
    }
  }
  y[0] = zb[0] * rdv[0];
#pragma unroll
  for (int k = 1; k < 8; ++k) {
    float a = zb[k];
#pragma unroll
    for (int m = 0; m < 8; ++m)
      if (m < k) a -= lp[k][m] * y[m];
    y[k] = a * rdv[k];
  }
  float zn = z;
#pragma unroll
  for (int c = 0; c < 8; ++c) zn -= v[c] * y[c];
#pragma unroll
  for (int c = 0; c < 8; ++c) {
    const bool okc = rok && (t > c) && (t - c <= 48);
    float* bp = okc ? &S[row * BSTR + (t - c)] : &S[dumidx];
    *bp = v[c];
    CP[c][t] = okc ? v[c] : 0.f;
  }
  if (t < 8) {
    float yv = y[0], rv = rdv[0];
#pragma unroll
    for (int k = 1; k < 8; ++k) {
      yv = (t == k) ? y[k] : yv;
      rv = (t == k) ? rdv[k] : rv;
    }
    RHS_s[row] = yv;
    RD_s[row] = rv;
  } else {
    float* rp = rok ? &RHS_s[row] : &DUMW[t & 63];
    *rp = zn;
  }
}

// ---------------------------------------------------------------------------
// backward panel scale on the flipped matrix. flipped row rr = jf + t;
// panel column c is flipped col jf+c, i.e. B[rr][jf+c] = B[rr][rr-(t-c)],
// stored at S[(575-rr+(t-c))*50 + (t-c)].  (R11 bug: used c, not t-c.)
// Valid flipped rows <= 287.
// ---------------------------------------------------------------------------
__device__ __forceinline__ void scale_panel_b(
    float* __restrict__ S, float* RHS_s, float* RD_s, float (*CP)[64],
    float* DUMW, int t, int jf, int dumidx)
{
  const int rr = jf + t;
  const bool rok = rr <= 287;
  float v[8];
#pragma unroll
  for (int c = 0; c < 8; ++c) {
    const bool okc = rok && (t >= c) && (t - c <= 48);
    const int addr = okc ? ((575 - rr + (t - c)) * BSTR + (t - c)) : dumidx;
    float vv = S[addr];
    v[c] = okc ? vv : 0.f;
  }
  float zb[8];
#pragma unroll
  for (int k = 0; k < 8; ++k) zb[k] = RHS_s[575 - (jf + k)];
  float z = RHS_s[rok ? (575 - rr) : (575 - jf)];
  z = rok ? z : 0.f;
  float rdv[8], y[8], lp[8][8];
#pragma unroll
  for (int k = 0; k < 8; ++k) {
    if (k == 0) rdv[0] = RD_s[575 - jf];
    else rdv[k] = rsqrtf(rdlane(v[k], k));
    v[k] *= rdv[k];
#pragma unroll
    for (int m = k + 1; m < 8; ++m) {
      lp[m][k] = rdlane(v[k], m);
      v[m] -= v[k] * lp[m][k];
    }
  }
  y[0] = zb[0] * rdv[0];
#pragma unroll
  for (int k = 1; k < 8; ++k) {
    float a = zb[k];
#pragma unroll
    for (int m = 0; m < 8; ++m)
      if (m < k) a -= lp[k][m] * y[m];
    y[k] = a * rdv[k];
  }
  float zn = z;
#pragma unroll
  for (int c = 0; c < 8; ++c) zn -= v[c] * y[c];
#pragma unroll
  for (int c = 0; c < 8; ++c) {
    const bool okc = rok && (t > c) && (t - c <= 48);
    float* bp = okc ? &S[(575 - rr + (t - c)) * BSTR + (t - c)] : &S[dumidx];
    *bp = v[c];
    CP[c][t] = okc ? v[c] : 0.f;
  }
  if (t < 8) {
    float yv = y[0], rv = rdv[0];
#pragma unroll
    for (int k = 1; k < 8; ++k) {
      yv = (t == k) ? y[k] : yv;
      rv = (t == k) ? rdv[k] : rv;
    }
    RHS_s[575 - rr] = yv;
    RD_s[575 - rr] = rv;
  } else {
    float* rp = rok ? &RHS_s[575 - rr] : &DUMW[t & 63];
    *rp = zn;
  }
}

// ---------------------------------------------------------------------------
// Twisted (BABE) banded Cholesky solver. 512 threads per system b = n*16+g.
// Block-Cholesky of the permuted system [fwd 0..239 | flip(575..336) |
// mid 240..335]; A_fb == 0 since the index gap (97) > bandwidth (48).
// 30 concurrent supersteps (wave0 fwd scale || wave1 bwd scale; disjoint
// trailing updates rows<=287 / rows>=288) + 12 middle supersteps.
// Solve: fused z during factor; middle BS + mirrored tail; then fwd/bwd BS
// concurrently on waves 0/1. + GroupNorm stat accumulation.
// ---------------------------------------------------------------------------
__global__ __launch_bounds__(CTH, 1) void chol_kernel(
    const float* __restrict__ att, const float* __restrict__ grd,
    float* __restrict__ sol, double* __restrict__ acc)
{
  extern __shared__ float S[];          // [28800] band + [CTH] dummy sink
  __shared__ float RHS_s[NUM];
  __shared__ float RD_s[NUM];
  __shared__ float XS_s[NUM];
  __shared__ __align__(16) float CPF[8][64];
  __shared__ __align__(16) float CPB[8][64];
  __shared__ float DUMW[64];
  __shared__ double RW[16];
  const int b = blockIdx.x, tid = threadIdx.x;
  const int n = b >> 4, g = b & 15;
  const float* ac = att + (size_t)(n * 64 + g * 4) * 576;
  const float* gc = grd + (size_t)(n * 64 + g * 4) * 576;
  const int dumidx = NUM * BSTR + tid;

  // --- tile decodes: triangle (U,W), 0<=W<=U<=23, T = U(U+1)/2+W; r = 8+2*.
  int r1A, r2A, r1B, r2B;
  const bool okA = tid < 300;
  const int btid = (tid >= 300) ? (tid - 300) : ((tid < 88) ? (tid + 212) : -1);
  const bool okB = btid >= 0;
  {
    int T = okA ? tid : 0;
    int U = (int)((sqrtf(8.f * (float)T + 1.f) - 1.f) * 0.5f);
    while (U * (U + 1) / 2 > T) --U;
    while ((U + 1) * (U + 2) / 2 <= T) ++U;
    int W = T - U * (U + 1) / 2;
    r1A = 8 + 2 * U; r2A = 8 + 2 * W;
    T = okB ? btid : 0;
    U = (int)((sqrtf(8.f * (float)T + 1.f) - 1.f) * 0.5f);
    while (U * (U + 1) / 2 > T) --U;
    while ((U + 1) * (U + 2) / 2 <= T) ++U;
    W = T - U * (U + 1) / 2;
    r1B = 8 + 2 * U; r2B = 8 + 2 * W;
  }

  // --- zero band
  for (int i = tid; i < NUM * BSTR; i += CTH) S[i] = 0.f;
  __syncthreads();

  // --- assemble band + rhs (verified math), seed rd[0] and rd[575]
  for (int i = tid; i < NUM; i += CTH) {
    float diag = 1e-12f, rv = 0.f;
    float od1 = 0.f, od2 = 0.f, od24 = 0.f, od48 = 0.f;
    if (((i + 1) % 24 != 0) && (i + 1 < NUM)) {
      float a0 = ac[0 * 576 + i]; float s = a0 * a0;
      diag += s; rv += s * gc[0 * 576 + i];
    }
    if (i - 1 >= 0 && (i % 24 != 0)) {
      float a0 = ac[0 * 576 + (i - 1)]; float s = a0 * a0;
      diag += s; rv -= s * gc[0 * 576 + (i - 1)]; od1 = -s;
    }
    if (i + 24 < NUM) {
      float a1 = ac[1 * 576 + i]; float s = a1 * a1;
      diag += s; rv += s * gc[1 * 576 + i];
    }
    if (i - 24 >= 0) {
      float a1 = ac[1 * 576 + (i - 24)]; float s = a1 * a1;
      diag += s; rv -= s * gc[1 * 576 + (i - 24)]; od24 = -s;
    }
    if (((i + 2) % 24 != 0) && (i + 2 < NUM)) {
      float a2 = ac[2 * 576 + i]; float s = a2 * a2;
      diag += s; rv += s * gc[2 * 576 + i];
    }
    if (i - 2 >= 0 && (i % 24 != 0)) {
      float a2 = ac[2 * 576 + (i - 2)]; float s = a2 * a2;
      diag += s; rv -= s * gc[2 * 576 + (i - 2)]; od2 = -s;
    }
    if (i + 48 < NUM) {
      float a3 = ac[3 * 576 + i]; float s = a3 * a3;
      diag += s; rv += s * gc[3 * 576 + i];
    }
    if (i - 48 >= 0) {
      float a3 = ac[3 * 576 + (i - 48)]; float s = a3 * a3;
      diag += s; rv -= s * gc[3 * 576 + (i - 48)]; od48 = -s;
    }
    if (i == NUM - 1) {
#pragma unroll
      for (int t = 0; t < 4; ++t) {
        float a = ac[t * 576 + (NUM - 1)]; float s = a * a;
        diag += s; rv += s * gc[t * 576 + (NUM - 1)];
      }
    }
    S[i * BSTR + 0] = diag;
    S[i * BSTR + 1] = od1;
    S[i * BSTR + 2] = od2;
    S[i * BSTR + 24] = od24;
    S[i * BSTR + 48] = od48;
    RHS_s[i] = rv;
    if (i == 0) RD_s[0] = rsqrtf(diag);
    if (i == NUM - 1) RD_s[NUM - 1] = rsqrtf(diag);
  }

  // --- concurrent fwd/bwd factorization: 30 supersteps
  for (int s = 0; s < 30; ++s) {
    const int j = 8 * s;
    __syncthreads();
    if (tid < 64)
      scale_panel_f(S, RHS_s, RD_s, CPF, DUMW, tid, j, 287, dumidx);
    else if (tid < 128)
      scale_panel_b(S, RHS_s, RD_s, CPB, DUMW, tid - 64, j, dumidx);
    __syncthreads();
    // fwd tiles (rows <= 287 automatically)
    {
      float2 cr[8], cc[8];
#pragma unroll
      for (int c = 0; c < 8; ++c) {
        cr[c] = *(const float2*)&CPF[c][r1A];
        cc[c] = *(const float2*)&CPF[c][r2A];
      }
      float s00 = 0.f, s01 = 0.f, s10 = 0.f, s11 = 0.f;
#pragma unroll
      for (int c = 0; c < 8; ++c) {
        s00 += cr[c].x * cc[c].x; s01 += cr[c].x * cc[c].y;
        s10 += cr[c].y * cc[c].x; s11 += cr[c].y * cc[c].y;
      }
      const int p00 = j * BSTR + 51 * r1A - r2A;
      float* q00 = okA ? &S[p00] : &S[dumidx];
      float* q01 = okA ? &S[p00 - 1] : &S[dumidx];
      float* q10 = okA ? &S[p00 + 51] : &S[dumidx];
      float* q11 = okA ? &S[p00 + 50] : &S[dumidx];
      const float t00 = *q00 - s00, t01 = *q01 - s01;
      const float t10 = *q10 - s10, t11 = *q11 - s11;
      *q00 = t00; *q01 = t01; *q10 = t10; *q11 = t11;
      if (tid == 0) RD_s[j + 8] = rsqrtf(t00);   // j+8 <= 240 (middle seed at j=232)
    }
    // bwd tiles (slot rows >= 288 automatically)
    {
      float2 cr[8], cc[8];
#pragma unroll
      for (int c = 0; c < 8; ++c) {
        cr[c] = *(const float2*)&CPB[c][r1B];
        cc[c] = *(const float2*)&CPB[c][r2B];
      }
      float s00 = 0.f, s01 = 0.f, s10 = 0.f, s11 = 0.f;
#pragma unroll
      for (int c = 0; c < 8; ++c) {
        s00 += cr[c].x * cc[c].x; s01 += cr[c].x * cc[c].y;
        s10 += cr[c].y * cc[c].x; s11 += cr[c].y * cc[c].y;
      }
      const int p00b = (575 - j - r2B) * BSTR + (r1B - r2B);
      float* q00 = okB ? &S[p00b] : &S[dumidx];
      float* q01 = okB ? &S[p00b - 51] : &S[dumidx];   // (r1, r2+1)
      float* q10 = okB ? &S[p00b + 1] : &S[dumidx];    // (r1+1, r2)
      float* q11 = okB ? &S[p00b - 50] : &S[dumidx];   // (r1+1, r2+1)
      const float t00 = *q00 - s00, t01 = *q01 - s01;
      const float t10 = *q10 - s10, t11 = *q11 - s11;
      *q00 = t00; *q01 = t01; *q10 = t10; *q11 = t11;
      if (btid == 0 && j + 8 <= 239) RD_s[575 - (j + 8)] = rsqrtf(t00);
    }
  }

  // --- middle factorization: 12 supersteps on rows/cols [240, 335]
  for (int j = 240; j < 336; j += 8) {
    __syncthreads();
    if (tid < 64)
      scale_panel_f(S, RHS_s, RD_s, CPF, DUMW, tid, j, 335, dumidx);
    __syncthreads();
    const int R = 335 - j;
    {
      const bool a0 = okA && (r1A <= R);
      const bool a1 = okA && (r1A + 1 <= R);
      float2 cr[8], cc[8];
#pragma unroll
      for (int c = 0; c < 8; ++c) {
        cr[c] = *(const float2*)&CPF[c][r1A];
        cc[c] = *(const float2*)&CPF[c][r2A];
      }
      float s00 = 0.f, s01 = 0.f, s10 = 0.f, s11 = 0.f;
#pragma unroll
      for (int c = 0; c < 8; ++c) {
        s00 += cr[c].x * cc[c].x; s01 += cr[c].x * cc[c].y;
        s10 += cr[c].y * cc[c].x; s11 += cr[c].y * cc[c].y;
      }
      const int p00 = j * BSTR + 51 * r1A - r2A;
      float* q00 = a0 ? &S[p00] : &S[dumidx];
      float* q01 = a0 ? &S[p00 - 1] : &S[dumidx];
      float* q10 = a1 ? &S[p00 + 51] : &S[dumidx];
      float* q11 = a1 ? &S[p00 + 50] : &S[dumidx];
      const float t00 = *q00 - s00, t01 = *q01 - s01;
      const float t10 = *q10 - s10, t11 = *q11 - s11;
      *q00 = t00; *q01 = t01; *q10 = t10; *q11 = t11;
      if (tid == 0 && a0) RD_s[j + 8] = rsqrtf(t00);
    }
  }
  __syncthreads();

  // --- middle back substitution (wave 0): blocks 335..247; tails reach
  //     rows < 240 applying Cf^T x_mid to fwd y automatically.
  if (tid < 64) {
    const int t = tid;
    for (int i = 335; i >= 247; i -= 8) {
      asm volatile("s_waitcnt lgkmcnt(0)" ::: "memory");
      float zz[8], rr2[8];
#pragma unroll
      for (int k = 0; k < 8; ++k) { zz[k] = RHS_s[i - k]; rr2[k] = RD_s[i - k]; }
      float L[8][8];
#pragma unroll
      for (int a = 0; a < 8; ++a)
#pragma unroll
        for (int bb = 0; bb < 8; ++bb)
          if (bb > a) L[a][bb] = S[(i - a) * BSTR + (bb - a)];
      float x[8];
      x[0] = zz[0] * rr2[0];
#pragma unroll
      for (int k = 1; k < 8; ++k) {
        float a2 = zz[k];
#pragma unroll
        for (int m = 0; m < 8; ++m)
          if (m < k) a2 -= L[m][k] * x[m];
        x[k] = a2 * rr2[k];
      }
      const int rb = i - 8 - t;
      const bool bok = rb >= 0;
      float acc2 = 0.f;
#pragma unroll
      for (int k = 0; k < 8; ++k) {
        const int d = 8 + t - k;
        const bool ok = bok && (d <= 48);
        float Lv = S[ok ? ((i - k) * BSTR + d) : dumidx];
        Lv = ok ? Lv : 0.f;
        acc2 += Lv * x[k];
      }
      const float zbv = RHS_s[bok ? rb : 0];
      float* rp = bok ? &RHS_s[rb] : &DUMW[t];
      *rp = zbv - acc2;
      float xv = x[0];
#pragma unroll
      for (int k = 1; k < 8; ++k) xv = (t == k) ? x[k] : xv;
      if (t < 8) XS_s[i - t] = xv;
    }
  }
  __syncthreads();

  // --- mirrored tail: y_b[jj] -= Cb^T x_mid for bwd rows jj in [336, 383]
  if (tid < 48) {
    const int jj = 336 + tid;
    float sacc = 0.f;
    for (int i = jj - 48; i <= 335; ++i)
      sacc += S[jj * BSTR + (jj - i)] * XS_s[i];
    RHS_s[jj] -= sacc;
  }
  __syncthreads();

  // --- concurrent fwd (wave 0) / bwd (wave 1) back substitutions
  if (tid < 64) {
    const int t = tid;
    for (int i = 239; i >= 7; i -= 8) {
      asm volatile("s_waitcnt lgkmcnt(0)" ::: "memory");
      float zz[8], rr2[8];
#pragma unroll
      for (int k = 0; k < 8; ++k) { zz[k] = RHS_s[i - k]; rr2[k] = RD_s[i - k]; }
      float L[8][8];
#pragma unroll
      for (int a = 0; a < 8; ++a)
#pragma unroll
        for (int bb = 0; bb < 8; ++bb)
          if (bb > a) L[a][bb] = S[(i - a) * BSTR + (bb - a)];
      float x[8];
      x[0] = zz[0] * rr2[0];
#pragma unroll
      for (int k = 1; k < 8; ++k) {
        float a2 = zz[k];
#pragma unroll
        for (int m = 0; m < 8; ++m)
          if (m < k) a2 -= L[m][k] * x[m];
        x[k] = a2 * rr2[k];
      }
      const int rb = i - 8 - t;
      const bool bok = rb >= 0;
      float acc2 = 0.f;
#pragma unroll
      for (int k = 0; k < 8; ++k) {
        const int d = 8 + t - k;
        const bool ok = bok && (d <= 48);
        float Lv = S[ok ? ((i - k) * BSTR + d) : dumidx];
        Lv = ok ? Lv : 0.f;
        acc2 += Lv * x[k];
      }
      const float zbv = RHS_s[bok ? rb : 0];
      float* rp = bok ? &RHS_s[rb] : &DUMW[t];
      *rp = zbv - acc2;
      float xv = x[0];
#pragma unroll
      for (int k = 1; k < 8; ++k) xv = (t == k) ? x[k] : xv;
      if (t < 8) XS_s[i - t] = xv;
    }
  } else if (tid < 128) {
    const int t = tid - 64;
    for (int i = 239; i >= 7; i -= 8) {
      asm volatile("s_waitcnt lgkmcnt(0)" ::: "memory");
      float zz[8], rr2[8];
#pragma unroll
      for (int k = 0; k < 8; ++k) {
        zz[k] = RHS_s[575 - (i - k)];
        rr2[k] = RD_s[575 - (i - k)];
      }
      float L[8][8];
#pragma unroll
      for (int a = 0; a < 8; ++a)
#pragma unroll
        for (int bb = 0; bb < 8; ++bb)
          if (bb > a) L[a][bb] = S[(575 - (i - bb)) * BSTR + (bb - a)];
      float x[8];
      x[0] = zz[0] * rr2[0];
#pragma unroll
      for (int k = 1; k < 8; ++k) {
        float a2 = zz[k];
#pragma unroll
        for (int m = 0; m < 8; ++m)
          if (m < k) a2 -= L[m][k] * x[m];
        x[k] = a2 * rr2[k];
      }
      const int rb = i - 8 - t;
      const bool bok = rb >= 0;
      float acc2 = 0.f;
#pragma unroll
      for (int k = 0; k < 8; ++k) {
        const int d = 8 + t - k;
        const bool ok = bok && (d <= 48);
        float Lv = S[ok ? ((575 - rb) * BSTR + d) : dumidx];
        Lv = ok ? Lv : 0.f;
        acc2 += Lv * x[k];
      }
      const float zbv = RHS_s[bok ? (575 - rb) : 575];
      float* rp = bok ? &RHS_s[575 - rb] : &DUMW[t];
      *rp = zbv - acc2;
      float xv = x[0];
#pragma unroll
      for (int k = 1; k < 8; ++k) xv = (t == k) ? x[k] : xv;
      if (t < 8) XS_s[575 - (i - t)] = xv;
    }
  }
  __syncthreads();

  // --- write solution + accumulate GroupNorm stats (double)
  double ls = 0.0, ls2 = 0.0;
  for (int i = tid; i < NUM; i += CTH) {
    const float xv = XS_s[i];
    sol[(size_t)b * NUM + i] = xv;
    ls += (double)xv;
    ls2 += (double)xv * (double)xv;
  }
#pragma unroll
  for (int off = 32; off > 0; off >>= 1) {
    ls += __shfl_down(ls, off);
    ls2 += __shfl_down(ls2, off);
  }
  if ((tid & 63) == 0) {
    RW[(tid >> 6) * 2] = ls;
    RW[(tid >> 6) * 2 + 1] = ls2;
  }
  __syncthreads();
  if (tid == 0) {
    double s = 0.0, s2 = 0.0;
#pragma unroll
    for (int wv = 0; wv < 8; ++wv) { s += RW[wv * 2]; s2 += RW[wv * 2 + 1]; }
    atomicAdd(&acc[n * 2], s);
    atomicAdd(&acc[n * 2 + 1], s2);
  }
}

// ---------------------------------------------------------------------------
// post conv fused with GroupNorm-apply + SE scale (halo-padded staging).
// ---------------------------------------------------------------------------
__global__ __launch_bounds__(576) void postgn_kernel(
    const float* __restrict__ sol, const double* __restrict__ acc,
    const float* __restrict__ sev,
    const float* __restrict__ gnw, const float* __restrict__ gnb,
    const float* __restrict__ w, const float* __restrict__ bias,
    float* __restrict__ out)
{
  __shared__ float sy[16 * 676];
  const int co = blockIdx.x, n = blockIdx.y, tid = threadIdx.x;
  const double mu_d = acc[n * 2] * (1.0 / 9216.0);
  const double var_d = acc[n * 2 + 1] * (1.0 / 9216.0) - mu_d * mu_d;
  const float rstd = (float)(1.0 / sqrt(var_d + 1e-5));
  const float muf = (float)mu_d;
  for (int i = tid; i < 16 * 676; i += 576) sy[i] = 0.f;
  __syncthreads();
#pragma unroll
  for (int q = 0; q < 4; ++q) {
    const int p = tid + q * 576;
    const int k = p / 144;
    const int r = p - k * 144;
    const int pix = r * 4;
    const int ppy = pix / 24, ppx = pix - ppy * 24;
    const float sv = sev[n * 16 + k];
    const float gw = gnw[k] * rstd;
    const float A = gw * sv;
    const float B = (gnb[k] - muf * gw) * sv;
    const float4 v = *(const float4*)&sol[(size_t)n * 9216 + p * 4];
    float* d = &sy[k * 676 + (ppy + 1) * 26 + ppx + 1];
    d[0] = v.x * A + B; d[1] = v.y * A + B;
    d[2] = v.z * A + B; d[3] = v.w * A + B;
  }
  __syncthreads();
  const int py = tid / 24, px = tid - py * 24;
  const int hb0 = py * 26 + px;
  float a = bias[co];
#pragma unroll 4
  for (int k = 0; k < 16; ++k) {
    const float* wp = w + (co * 16 + k) * 9;
    const float* sp = &sy[k * 676 + hb0];
#pragma unroll
    for (int dy = 0; dy < 3; ++dy)
#pragma unroll
      for (int dx = 0; dx < 3; ++dx)
        a += sp[dy * 26 + dx] * wp[dy * 3 + dx];
  }
  out[(size_t)(n * 128 + co) * 576 + tid] = a;
}

// ---------------------------------------------------------------------------
extern "C" void kernel_launch(void* const* d_in, const int* in_sizes, int n_in,
                              void* d_out, int out_size, void* d_ws, size_t ws_size,
                              hipStream_t stream) {
  const float* x       = (const float*)d_in[0];
  const float* grad_w1 = (const float*)d_in[2];
  const float* grad_b1 = (const float*)d_in[3];
  const float* grad_w2 = (const float*)d_in[4];
  const float* grad_b2 = (const float*)d_in[5];
  const float* att_w1  = (const float*)d_in[6];
  const float* att_b1  = (const float*)d_in[7];
  const float* att_w2  = (const float*)d_in[8];
  const float* att_b2  = (const float*)d_in[9];
  const float* se_w1   = (const float*)d_in[10];
  const float* se_b1   = (const float*)d_in[11];
  const float* se_w2   = (const float*)d_in[12];
  const float* se_b2   = (const float*)d_in[13];
  const float* gn_w    = (const float*)d_in[14];
  const float* gn_b    = (const float*)d_in[15];
  const float* post_w  = (const float*)d_in[16];
  const float* post_b  = (const float*)d_in[17];
  float* out = (float*)d_out;

  float* ws  = (float*)d_ws;
  float* t1a = ws;              // 147456
  float* t1g = t1a + 147456;    // 147456
  float* att = t1g + 147456;    // 147456
  float* grd = att + 147456;    // 147456
  float* sev = grd + 147456;    // 64
  float* sol = sev + 64;        // 36864
  double* acc = (double*)(sol + 36864);  // 8 doubles

  (void)hipFuncSetAttribute((const void*)chol_kernel,
                            hipFuncAttributeMaxDynamicSharedMemorySize,
                            (int)CHOL_LDS_BYTES);

  conv1se_kernel<<<dim3(65, 4), 576, 0, stream>>>(
      x, att_w1, att_b1, grad_w1, grad_b1,
      se_w1, se_b1, se_w2, se_b2, t1a, t1g, sev, acc);
  conv2_kernel<<<dim3(64, 4, 2), 576, 0, stream>>>(t1a, t1g, att_w2, att_b2,
                                                   grad_w2, grad_b2, att, grd);
  chol_kernel<<<64, CTH, CHOL_LDS_BYTES, stream>>>(att, grd, sol, acc);
  postgn_kernel<<<dim3(128, 4), 576, 0, stream>>>(sol, acc, sev, gn_w, gn_b,
                                                  post_w, post_b, out);
}

// Round 13
// 170.381 us; speedup vs baseline: 1.2201x; 1.0096x over previous
//
#include <hip/hip_runtime.h>
#include <math.h>

#define NUM 576
#define BSTR 50
#define CTH 512
// dynamic LDS: band (576*50) + CTH-float dummy sink
#define CHOL_LDS_BYTES ((NUM * BSTR + CTH) * sizeof(float))

__device__ __forceinline__ float leakyf(float v) { return v > 0.f ? v : 0.01f * v; }
__device__ __forceinline__ float sigmoidf(float v) { return 1.f / (1.f + __expf(-v)); }
__device__ __forceinline__ float rdlane(float v, int l) {
  return __uint_as_float(__builtin_amdgcn_readlane(__float_as_uint(v), l));
}

// ---------------------------------------------------------------------------
// conv1 + SE fused (halo-padded staging).
// ---------------------------------------------------------------------------
__global__ __launch_bounds__(576) void conv1se_kernel(
    const float* __restrict__ x,
    const float* __restrict__ wa, const float* __restrict__ ba,
    const float* __restrict__ wg, const float* __restrict__ bg,
    const float* __restrict__ sw1, const float* __restrict__ sb1,
    const float* __restrict__ sw2, const float* __restrict__ sb2,
    float* __restrict__ outa, float* __restrict__ outg,
    float* __restrict__ sev, double* __restrict__ acc)
{
  __shared__ float sx[16 * 676];
  __shared__ float pooled[64];
  __shared__ float hid[32];
  const int co = blockIdx.x, n = blockIdx.y;
  const int tid = threadIdx.x;

  if (co == 64) {
    if (tid < 2) acc[n * 2 + tid] = 0.0;
    if (tid < 64) {
      const float4* xp4 = (const float4*)(x + (size_t)(n * 64 + tid) * 576);
      float s = 0.f;
      for (int p = 0; p < 144; ++p) {
        float4 v = xp4[p];
        s += v.x + v.y + v.z + v.w;
      }
      pooled[tid] = s * (1.f / 576.f);
    }
    __syncthreads();
    if (tid < 32) {
      float h = sb1[tid];
      for (int c = 0; c < 64; ++c) h += pooled[c] * sw1[tid * 64 + c];
      hid[tid] = leakyf(h);
    }
    __syncthreads();
    if (tid < 16) {
      float v = sb2[tid];
      for (int j = 0; j < 32; ++j) v += hid[j] * sw2[tid * 32 + j];
      sev[n * 16 + tid] = sigmoidf(v);
    }
    return;
  }

  const int py = tid / 24, px = tid - py * 24;
  const int hb0 = py * 26 + px;
  for (int i = tid; i < 16 * 676; i += 576) sx[i] = 0.f;
  float acc_a = ba[co];
  float acc_g = bg[co];
  for (int c0 = 0; c0 < 64; c0 += 16) {
    __syncthreads();
#pragma unroll
    for (int q = 0; q < 4; ++q) {
      const int p = tid + q * 576;
      const int k = p / 144;
      const int r = p - k * 144;
      const int pix = r * 4;
      const int ppy = pix / 24, ppx = pix - ppy * 24;
      const float4 v = *(const float4*)&x[(size_t)(n * 64 + c0) * 576 + p * 4];
      float* d = &sx[k * 676 + (ppy + 1) * 26 + ppx + 1];
      d[0] = v.x; d[1] = v.y; d[2] = v.z; d[3] = v.w;
    }
    __syncthreads();
#pragma unroll 4
    for (int k = 0; k < 16; ++k) {
      const float* wpa = wa + (co * 64 + c0 + k) * 9;
      const float* wpg = wg + (co * 64 + c0 + k) * 9;
      const float* sp = &sx[k * 676 + hb0];
#pragma unroll
      for (int dy = 0; dy < 3; ++dy)
#pragma unroll
        for (int dx = 0; dx < 3; ++dx) {
          const float v = sp[dy * 26 + dx];
          acc_a += v * wpa[dy * 3 + dx];
          acc_g += v * wpg[dy * 3 + dx];
        }
    }
  }
  const int o = (n * 64 + co) * 576 + tid;
  outa[o] = leakyf(acc_a);
  outg[o] = leakyf(acc_g);
}

// ---------------------------------------------------------------------------
// conv2 (halo-padded staging).
// ---------------------------------------------------------------------------
__global__ __launch_bounds__(576) void conv2_kernel(
    const float* __restrict__ t1a, const float* __restrict__ t1g,
    const float* __restrict__ wa, const float* __restrict__ ba,
    const float* __restrict__ wg, const float* __restrict__ bg,
    float* __restrict__ att, float* __restrict__ grd)
{
  __shared__ float sx[16 * 676];
  const int co = blockIdx.x, n = blockIdx.y, br = blockIdx.z;
  const float* src = br ? t1g : t1a;
  const float* wp0 = br ? wg : wa;
  const float bias = br ? bg[co] : ba[co];
  float* dst = br ? grd : att;
  const int tid = threadIdx.x;
  const int py = tid / 24, px = tid - py * 24;
  const int hb0 = py * 26 + px;
  for (int i = tid; i < 16 * 676; i += 576) sx[i] = 0.f;
  float acc = bias;
  for (int c0 = 0; c0 < 64; c0 += 16) {
    __syncthreads();
#pragma unroll
    for (int q = 0; q < 4; ++q) {
      const int p = tid + q * 576;
      const int k = p / 144;
      const int r = p - k * 144;
      const int pix = r * 4;
      const int ppy = pix / 24, ppx = pix - ppy * 24;
      const float4 v = *(const float4*)&src[(size_t)(n * 64 + c0) * 576 + p * 4];
      float* d = &sx[k * 676 + (ppy + 1) * 26 + ppx + 1];
      d[0] = v.x; d[1] = v.y; d[2] = v.z; d[3] = v.w;
    }
    __syncthreads();
#pragma unroll 4
    for (int k = 0; k < 16; ++k) {
      const float* wp = wp0 + (co * 64 + c0 + k) * 9;
      const float* sp = &sx[k * 676 + hb0];
#pragma unroll
      for (int dy = 0; dy < 3; ++dy)
#pragma unroll
        for (int dx = 0; dx < 3; ++dx)
          acc += sp[dy * 26 + dx] * wp[dy * 3 + dx];
    }
  }
  if (br == 0) acc = sigmoidf(acc);
  dst[(n * 64 + co) * 576 + tid] = acc;
}

// ---------------------------------------------------------------------------
// forward/middle panel scale: in-register 8-col micro-Cholesky + fused z-sub.
// maxrow clips both L-stores and RHS writes (287 fwd / 335 middle).
// ---------------------------------------------------------------------------
__device__ __forceinline__ void scale_panel_f(
    float* __restrict__ S, float* RHS_s, float* RD_s, float (*CP)[64],
    float* DUMW, int t, int j, int maxrow, int dumidx)
{
  const int row = j + t;
  const bool rok = row <= maxrow;
  float v[8];
#pragma unroll
  for (int c = 0; c < 8; ++c) {
    const bool okc = rok && (t >= c) && (t - c <= 48);
    const int addr = okc ? (row * BSTR + (t - c)) : dumidx;
    float vv = S[addr];
    v[c] = okc ? vv : 0.f;
  }
  float zb[8];
#pragma unroll
  for (int k = 0; k < 8; ++k) zb[k] = RHS_s[j + k];
  float z = RHS_s[rok ? row : j];
  z = rok ? z : 0.f;
  float rdv[8], y[8], lp[8][8];
#pragma unroll
  for (int k = 0; k < 8; ++k) {
    if (k == 0) rdv[0] = RD_s[j];
    else rdv[k] = rsqrtf(rdlane(v[k], k));
    v[k] *= rdv[k];
#pragma unroll
    for (int m = k + 1; m < 8; ++m) {
      lp[m][k] = rdlane(v[k], m);
      v[m] -= v[k] * lp[m][k];
    }
  }
  y[0] = zb[0] * rdv[0];
#pragma unroll
  for (int k = 1; k < 8; ++k) {
    float a = zb[k];
#pragma unroll
    for (int m = 0; m < 8; ++m)
      if (m < k) a -= lp[k][m] * y[m];
    y[k] = a * rdv[k];
  }
  float zn = z;
#pragma unroll
  for (int c = 0; c < 8; ++c) zn -= v[c] * y[c];
#pragma unroll
  for (int c = 0; c < 8; ++c) {
    const bool okc = rok && (t > c) && (t - c <= 48);
    float* bp = okc ? &S[row * BSTR + (t - c)] : &S[dumidx];
    *bp = v[c];
    CP[c][t] = okc ? v[c] : 0.f;
  }
  if (t < 8) {
    float yv = y[0], rv = rdv[0];
#pragma unroll
    for (int k = 1; k < 8; ++k) {
      yv = (t == k) ? y[k] : yv;
      rv = (t == k) ? rdv[k] : rv;
    }
    RHS_s[row] = yv;
    RD_s[row] = rv;
  } else {
    float* rp = rok ? &RHS_s[row] : &DUMW[t & 63];
    *rp = zn;
  }
}

// ---------------------------------------------------------------------------
// backward panel scale on the flipped matrix. flipped row rr = jf + t;
// panel column c is flipped col jf+c, i.e. B[rr][jf+c] = B[rr][rr-(t-c)],
// stored at S[(575-rr+(t-c))*50 + (t-c)].  Valid flipped rows <= 287.
// ---------------------------------------------------------------------------
__device__ __forceinline__ void scale_panel_b(
    float* __restrict__ S, float* RHS_s, float* RD_s, float (*CP)[64],
    float* DUMW, int t, int jf, int dumidx)
{
  const int rr = jf + t;
  const bool rok = rr <= 287;
  float v[8];
#pragma unroll
  for (int c = 0; c < 8; ++c) {
    const bool okc = rok && (t >= c) && (t - c <= 48);
    const int addr = okc ? ((575 - rr + (t - c)) * BSTR + (t - c)) : dumidx;
    float vv = S[addr];
    v[c] = okc ? vv : 0.f;
  }
  float zb[8];
#pragma unroll
  for (int k = 0; k < 8; ++k) zb[k] = RHS_s[575 - (jf + k)];
  float z = RHS_s[rok ? (575 - rr) : (575 - jf)];
  z = rok ? z : 0.f;
  float rdv[8], y[8], lp[8][8];
#pragma unroll
  for (int k = 0; k < 8; ++k) {
    if (k == 0) rdv[0] = RD_s[575 - jf];
    else rdv[k] = rsqrtf(rdlane(v[k], k));
    v[k] *= rdv[k];
#pragma unroll
    for (int m = k + 1; m < 8; ++m) {
      lp[m][k] = rdlane(v[k], m);
      v[m] -= v[k] * lp[m][k];
    }
  }
  y[0] = zb[0] * rdv[0];
#pragma unroll
  for (int k = 1; k < 8; ++k) {
    float a = zb[k];
#pragma unroll
    for (int m = 0; m < 8; ++m)
      if (m < k) a -= lp[k][m] * y[m];
    y[k] = a * rdv[k];
  }
  float zn = z;
#pragma unroll
  for (int c = 0; c < 8; ++c) zn -= v[c] * y[c];
#pragma unroll
  for (int c = 0; c < 8; ++c) {
    const bool okc = rok && (t > c) && (t - c <= 48);
    float* bp = okc ? &S[(575 - rr + (t - c)) * BSTR + (t - c)] : &S[dumidx];
    *bp = v[c];
    CP[c][t] = okc ? v[c] : 0.f;
  }
  if (t < 8) {
    float yv = y[0], rv = rdv[0];
#pragma unroll
    for (int k = 1; k < 8; ++k) {
      yv = (t == k) ? y[k] : yv;
      rv = (t == k) ? rdv[k] : rv;
    }
    RHS_s[575 - rr] = yv;
    RD_s[575 - rr] = rv;
  } else {
    float* rp = rok ? &RHS_s[575 - rr] : &DUMW[t & 63];
    *rp = zn;
  }
}

// ---------------------------------------------------------------------------
// Twisted (BABE) banded Cholesky solver. 512 threads per system b = n*16+g.
// Block-Cholesky of the permuted system [fwd 0..239 | flip(575..336) |
// mid 240..335]; A_fb == 0 since the index gap (97) > bandwidth (48).
// 30 concurrent supersteps (wave0 fwd scale || wave1 bwd scale; disjoint
// trailing updates rows<=287 / rows>=288) + 12 middle supersteps.
// Update targets (band cols >= j+8) are PREFETCHED before the scale barrier
// (disjoint from scale writes at cols <= j+7) so the RMW read hides under
// the serial scale chain. + GroupNorm stat accumulation.
// ---------------------------------------------------------------------------
__global__ __launch_bounds__(CTH, 1) void chol_kernel(
    const float* __restrict__ att, const float* __restrict__ grd,
    float* __restrict__ sol, double* __restrict__ acc)
{
  extern __shared__ float S[];          // [28800] band + [CTH] dummy sink
  __shared__ float RHS_s[NUM];
  __shared__ float RD_s[NUM];
  __shared__ float XS_s[NUM];
  __shared__ __align__(16) float CPF[8][64];
  __shared__ __align__(16) float CPB[8][64];
  __shared__ float DUMW[64];
  __shared__ double RW[16];
  const int b = blockIdx.x, tid = threadIdx.x;
  const int n = b >> 4, g = b & 15;
  const float* ac = att + (size_t)(n * 64 + g * 4) * 576;
  const float* gc = grd + (size_t)(n * 64 + g * 4) * 576;
  const int dumidx = NUM * BSTR + tid;

  // --- tile decodes: triangle (U,W), 0<=W<=U<=23, T = U(U+1)/2+W; r = 8+2*.
  int r1A, r2A, r1B, r2B;
  const bool okA = tid < 300;
  const int btid = (tid >= 300) ? (tid - 300) : ((tid < 88) ? (tid + 212) : -1);
  const bool okB = btid >= 0;
  {
    int T = okA ? tid : 0;
    int U = (int)((sqrtf(8.f * (float)T + 1.f) - 1.f) * 0.5f);
    while (U * (U + 1) / 2 > T) --U;
    while ((U + 1) * (U + 2) / 2 <= T) ++U;
    int W = T - U * (U + 1) / 2;
    r1A = 8 + 2 * U; r2A = 8 + 2 * W;
    T = okB ? btid : 0;
    U = (int)((sqrtf(8.f * (float)T + 1.f) - 1.f) * 0.5f);
    while (U * (U + 1) / 2 > T) --U;
    while ((U + 1) * (U + 2) / 2 <= T) ++U;
    W = T - U * (U + 1) / 2;
    r1B = 8 + 2 * U; r2B = 8 + 2 * W;
  }

  // --- zero band
  for (int i = tid; i < NUM * BSTR; i += CTH) S[i] = 0.f;
  __syncthreads();

  // --- assemble band + rhs (verified math), seed rd[0] and rd[575]
  for (int i = tid; i < NUM; i += CTH) {
    float diag = 1e-12f, rv = 0.f;
    float od1 = 0.f, od2 = 0.f, od24 = 0.f, od48 = 0.f;
    if (((i + 1) % 24 != 0) && (i + 1 < NUM)) {
      float a0 = ac[0 * 576 + i]; float s = a0 * a0;
      diag += s; rv += s * gc[0 * 576 + i];
    }
    if (i - 1 >= 0 && (i % 24 != 0)) {
      float a0 = ac[0 * 576 + (i - 1)]; float s = a0 * a0;
      diag += s; rv -= s * gc[0 * 576 + (i - 1)]; od1 = -s;
    }
    if (i + 24 < NUM) {
      float a1 = ac[1 * 576 + i]; float s = a1 * a1;
      diag += s; rv += s * gc[1 * 576 + i];
    }
    if (i - 24 >= 0) {
      float a1 = ac[1 * 576 + (i - 24)]; float s = a1 * a1;
      diag += s; rv -= s * gc[1 * 576 + (i - 24)]; od24 = -s;
    }
    if (((i + 2) % 24 != 0) && (i + 2 < NUM)) {
      float a2 = ac[2 * 576 + i]; float s = a2 * a2;
      diag += s; rv += s * gc[2 * 576 + i];
    }
    if (i - 2 >= 0 && (i % 24 != 0)) {
      float a2 = ac[2 * 576 + (i - 2)]; float s = a2 * a2;
      diag += s; rv -= s * gc[2 * 576 + (i - 2)]; od2 = -s;
    }
    if (i + 48 < NUM) {
      float a3 = ac[3 * 576 + i]; float s = a3 * a3;
      diag += s; rv += s * gc[3 * 576 + i];
    }
    if (i - 48 >= 0) {
      float a3 = ac[3 * 576 + (i - 48)]; float s = a3 * a3;
      diag += s; rv -= s * gc[3 * 576 + (i - 48)]; od48 = -s;
    }
    if (i == NUM - 1) {
#pragma unroll
      for (int t = 0; t < 4; ++t) {
        float a = ac[t * 576 + (NUM - 1)]; float s = a * a;
        diag += s; rv += s * gc[t * 576 + (NUM - 1)];
      }
    }
    S[i * BSTR + 0] = diag;
    S[i * BSTR + 1] = od1;
    S[i * BSTR + 2] = od2;
    S[i * BSTR + 24] = od24;
    S[i * BSTR + 48] = od48;
    RHS_s[i] = rv;
    if (i == 0) RD_s[0] = rsqrtf(diag);
    if (i == NUM - 1) RD_s[NUM - 1] = rsqrtf(diag);
  }

  // --- concurrent fwd/bwd factorization: 30 supersteps
  for (int s = 0; s < 30; ++s) {
    const int j = 8 * s;
    __syncthreads();
    // ---- target prefetch (disjoint from scale writes; hides RMW read)
    const int pF = j * BSTR + 51 * r1A - r2A;
    float* qF00 = okA ? &S[pF] : &S[dumidx];
    float* qF01 = okA ? &S[pF - 1] : &S[dumidx];
    float* qF10 = okA ? &S[pF + 51] : &S[dumidx];
    float* qF11 = okA ? &S[pF + 50] : &S[dumidx];
    const int pB = (575 - j - r2B) * BSTR + (r1B - r2B);
    float* qB00 = okB ? &S[pB] : &S[dumidx];
    float* qB01 = okB ? &S[pB - 51] : &S[dumidx];   // (r1, r2+1)
    float* qB10 = okB ? &S[pB + 1] : &S[dumidx];    // (r1+1, r2)
    float* qB11 = okB ? &S[pB - 50] : &S[dumidx];   // (r1+1, r2+1)
    const float vF00 = *qF00, vF01 = *qF01, vF10 = *qF10, vF11 = *qF11;
    const float vB00 = *qB00, vB01 = *qB01, vB10 = *qB10, vB11 = *qB11;
    if (tid < 64)
      scale_panel_f(S, RHS_s, RD_s, CPF, DUMW, tid, j, 287, dumidx);
    else if (tid < 128)
      scale_panel_b(S, RHS_s, RD_s, CPB, DUMW, tid - 64, j, dumidx);
    __syncthreads();
    // fwd tiles (rows <= 287 automatically)
    {
      float2 cr[8], cc[8];
#pragma unroll
      for (int c = 0; c < 8; ++c) {
        cr[c] = *(const float2*)&CPF[c][r1A];
        cc[c] = *(const float2*)&CPF[c][r2A];
      }
      float s00 = 0.f, s01 = 0.f, s10 = 0.f, s11 = 0.f;
#pragma unroll
      for (int c = 0; c < 8; ++c) {
        s00 += cr[c].x * cc[c].x; s01 += cr[c].x * cc[c].y;
        s10 += cr[c].y * cc[c].x; s11 += cr[c].y * cc[c].y;
      }
      const float t00 = vF00 - s00;
      *qF00 = t00; *qF01 = vF01 - s01;
      *qF10 = vF10 - s10; *qF11 = vF11 - s11;
      if (tid == 0) RD_s[j + 8] = rsqrtf(t00);   // middle seed at j=232
    }
    // bwd tiles (slot rows >= 288 automatically)
    {
      float2 cr[8], cc[8];
#pragma unroll
      for (int c = 0; c < 8; ++c) {
        cr[c] = *(const float2*)&CPB[c][r1B];
        cc[c] = *(const float2*)&CPB[c][r2B];
      }
      float s00 = 0.f, s01 = 0.f, s10 = 0.f, s11 = 0.f;
#pragma unroll
      for (int c = 0; c < 8; ++c) {
        s00 += cr[c].x * cc[c].x; s01 += cr[c].x * cc[c].y;
        s10 += cr[c].y * cc[c].x; s11 += cr[c].y * cc[c].y;
      }
      const float t00 = vB00 - s00;
      *qB00 = t00; *qB01 = vB01 - s01;
      *qB10 = vB10 - s10; *qB11 = vB11 - s11;
      if (btid == 0 && j + 8 <= 239) RD_s[575 - (j + 8)] = rsqrtf(t00);
    }
  }

  // --- middle factorization: 12 supersteps on rows/cols [240, 335]
  for (int j = 240; j < 336; j += 8) {
    __syncthreads();
    const int R = 335 - j;
    const bool a0 = okA && (r1A <= R);
    const bool a1 = okA && (r1A + 1 <= R);
    const int pM = j * BSTR + 51 * r1A - r2A;
    float* qM00 = a0 ? &S[pM] : &S[dumidx];
    float* qM01 = a0 ? &S[pM - 1] : &S[dumidx];
    float* qM10 = a1 ? &S[pM + 51] : &S[dumidx];
    float* qM11 = a1 ? &S[pM + 50] : &S[dumidx];
    const float vM00 = *qM00, vM01 = *qM01, vM10 = *qM10, vM11 = *qM11;
    if (tid < 64)
      scale_panel_f(S, RHS_s, RD_s, CPF, DUMW, tid, j, 335, dumidx);
    __syncthreads();
    {
      float2 cr[8], cc[8];
#pragma unroll
      for (int c = 0; c < 8; ++c) {
        cr[c] = *(const float2*)&CPF[c][r1A];
        cc[c] = *(const float2*)&CPF[c][r2A];
      }
      float s00 = 0.f, s01 = 0.f, s10 = 0.f, s11 = 0.f;
#pragma unroll
      for (int c = 0; c < 8; ++c) {
        s00 += cr[c].x * cc[c].x; s01 += cr[c].x * cc[c].y;
        s10 += cr[c].y * cc[c].x; s11 += cr[c].y * cc[c].y;
      }
      const float t00 = vM00 - s00;
      *qM00 = t00; *qM01 = vM01 - s01;
      *qM10 = vM10 - s10; *qM11 = vM11 - s11;
      if (tid == 0 && a0) RD_s[j + 8] = rsqrtf(t00);
    }
  }
  __syncthreads();

  // --- middle back substitution (wave 0): blocks 335..247; tails reach
  //     rows < 240 applying Cf^T x_mid to fwd y automatically.
  if (tid < 64) {
    const int t = tid;
    for (int i = 335; i >= 247; i -= 8) {
      asm volatile("s_waitcnt lgkmcnt(0)" ::: "memory");
      float zz[8], rr2[8];
#pragma unroll
      for (int k = 0; k < 8; ++k) { zz[k] = RHS_s[i - k]; rr2[k] = RD_s[i - k]; }
      float L[8][8];
#pragma unroll
      for (int a = 0; a < 8; ++a)
#pragma unroll
        for (int bb = 0; bb < 8; ++bb)
          if (bb > a) L[a][bb] = S[(i - a) * BSTR + (bb - a)];
      float x[8];
      x[0] = zz[0] * rr2[0];
#pragma unroll
      for (int k = 1; k < 8; ++k) {
        float a2 = zz[k];
#pragma unroll
        for (int m = 0; m < 8; ++m)
          if (m < k) a2 -= L[m][k] * x[m];
        x[k] = a2 * rr2[k];
      }
      const int rb = i - 8 - t;
      const bool bok = rb >= 0;
      float acc2 = 0.f;
#pragma unroll
      for (int k = 0; k < 8; ++k) {
        const int d = 8 + t - k;
        const bool ok = bok && (d <= 48);
        float Lv = S[ok ? ((i - k) * BSTR + d) : dumidx];
        Lv = ok ? Lv : 0.f;
        acc2 += Lv * x[k];
      }
      const float zbv = RHS_s[bok ? rb : 0];
      float* rp = bok ? &RHS_s[rb] : &DUMW[t];
      *rp = zbv - acc2;
      float xv = x[0];
#pragma unroll
      for (int k = 1; k < 8; ++k) xv = (t == k) ? x[k] : xv;
      if (t < 8) XS_s[i - t] = xv;
    }
  }
  __syncthreads();

  // --- mirrored tail: y_b[jj] -= Cb^T x_mid for bwd rows jj in [336, 383]
  if (tid < 48) {
    const int jj = 336 + tid;
    float sacc = 0.f;
    for (int i = jj - 48; i <= 335; ++i)
      sacc += S[jj * BSTR + (jj - i)] * XS_s[i];
    RHS_s[jj] -= sacc;
  }
  __syncthreads();

  // --- concurrent fwd (wave 0) / bwd (wave 1) back substitutions
  if (tid < 64) {
    const int t = tid;
    for (int i = 239; i >= 7; i -= 8) {
      asm volatile("s_waitcnt lgkmcnt(0)" ::: "memory");
      float zz[8], rr2[8];
#pragma unroll
      for (int k = 0; k < 8; ++k) { zz[k] = RHS_s[i - k]; rr2[k] = RD_s[i - k]; }
      float L[8][8];
#pragma unroll
      for (int a = 0; a < 8; ++a)
#pragma unroll
        for (int bb = 0; bb < 8; ++bb)
          if (bb > a) L[a][bb] = S[(i - a) * BSTR + (bb - a)];
      float x[8];
      x[0] = zz[0] * rr2[0];
#pragma unroll
      for (int k = 1; k < 8; ++k) {
        float a2 = zz[k];
#pragma unroll
        for (int m = 0; m < 8; ++m)
          if (m < k) a2 -= L[m][k] * x[m];
        x[k] = a2 * rr2[k];
      }
      const int rb = i - 8 - t;
      const bool bok = rb >= 0;
      float acc2 = 0.f;
#pragma unroll
      for (int k = 0; k < 8; ++k) {
        const int d = 8 + t - k;
        const bool ok = bok && (d <= 48);
        float Lv = S[ok ? ((i - k) * BSTR + d) : dumidx];
        Lv = ok ? Lv : 0.f;
        acc2 += Lv * x[k];
      }
      const float zbv = RHS_s[bok ? rb : 0];
      float* rp = bok ? &RHS_s[rb] : &DUMW[t];
      *rp = zbv - acc2;
      float xv = x[0];
#pragma unroll
      for (int k = 1; k < 8; ++k) xv = (t == k) ? x[k] : xv;
      if (t < 8) XS_s[i - t] = xv;
    }
  } else if (tid < 128) {
    const int t = tid - 64;
    for (int i = 239; i >= 7; i -= 8) {
      asm volatile("s_waitcnt lgkmcnt(0)" ::: "memory");
      float zz[8], rr2[8];
#pragma unroll
      for (int k = 0; k < 8; ++k) {
        zz[k] = RHS_s[575 - (i - k)];
        rr2[k] = RD_s[575 - (i - k)];
      }
      float L[8][8];
#pragma unroll
      for (int a = 0; a < 8; ++a)
#pragma unroll
        for (int bb = 0; bb < 8; ++bb)
          if (bb > a) L[a][bb] = S[(575 - (i - bb)) * BSTR + (bb - a)];
      float x[8];
      x[0] = zz[0] * rr2[0];
#pragma unroll
      for (int k = 1; k < 8; ++k) {
        float a2 = zz[k];
#pragma unroll
        for (int m = 0; m < 8; ++m)
          if (m < k) a2 -= L[m][k] * x[m];
        x[k] = a2 * rr2[k];
      }
      const int rb = i - 8 - t;
      const bool bok = rb >= 0;
      float acc2 = 0.f;
#pragma unroll
      for (int k = 0; k < 8; ++k) {
        const int d = 8 + t - k;
        const bool ok = bok && (d <= 48);
        float Lv = S[ok ? ((575 - rb) * BSTR + d) : dumidx];
        Lv = ok ? Lv : 0.f;
        acc2 += Lv * x[k];
      }
      const float zbv = RHS_s[bok ? (575 - rb) : 575];
      float* rp = bok ? &RHS_s[575 - rb] : &DUMW[t];
      *rp = zbv - acc2;
      float xv = x[0];
#pragma unroll
      for (int k = 1; k < 8; ++k) xv = (t == k) ? x[k] : xv;
      if (t < 8) XS_s[575 - (i - t)] = xv;
    }
  }
  __syncthreads();

  // --- write solution + accumulate GroupNorm stats (double)
  double ls = 0.0, ls2 = 0.0;
  for (int i = tid; i < NUM; i += CTH) {
    const float xv = XS_s[i];
    sol[(size_t)b * NUM + i] = xv;
    ls += (double)xv;
    ls2 += (double)xv * (double)xv;
  }
#pragma unroll
  for (int off = 32; off > 0; off >>= 1) {
    ls += __shfl_down(ls, off);
    ls2 += __shfl_down(ls2, off);
  }
  if ((tid & 63) == 0) {
    RW[(tid >> 6) * 2] = ls;
    RW[(tid >> 6) * 2 + 1] = ls2;
  }
  __syncthreads();
  if (tid == 0) {
    double s = 0.0, s2 = 0.0;
#pragma unroll
    for (int wv = 0; wv < 8; ++wv) { s += RW[wv * 2]; s2 += RW[wv * 2 + 1]; }
    atomicAdd(&acc[n * 2], s);
    atomicAdd(&acc[n * 2 + 1], s2);
  }
}

// ---------------------------------------------------------------------------
// post conv fused with GroupNorm-apply + SE scale (halo-padded staging).
// ---------------------------------------------------------------------------
__global__ __launch_bounds__(576) void postgn_kernel(
    const float* __restrict__ sol, const double* __restrict__ acc,
    const float* __restrict__ sev,
    const float* __restrict__ gnw, const float* __restrict__ gnb,
    const float* __restrict__ w, const float* __restrict__ bias,
    float* __restrict__ out)
{
  __shared__ float sy[16 * 676];
  const int co = blockIdx.x, n = blockIdx.y, tid = threadIdx.x;
  const double mu_d = acc[n * 2] * (1.0 / 9216.0);
  const double var_d = acc[n * 2 + 1] * (1.0 / 9216.0) - mu_d * mu_d;
  const float rstd = (float)(1.0 / sqrt(var_d + 1e-5));
  const float muf = (float)mu_d;
  for (int i = tid; i < 16 * 676; i += 576) sy[i] = 0.f;
  __syncthreads();
#pragma unroll
  for (int q = 0; q < 4; ++q) {
    const int p = tid + q * 576;
    const int k = p / 144;
    const int r = p - k * 144;
    const int pix = r * 4;
    const int ppy = pix / 24, ppx = pix - ppy * 24;
    const float sv = sev[n * 16 + k];
    const float gw = gnw[k] * rstd;
    const float A = gw * sv;
    const float B = (gnb[k] - muf * gw) * sv;
    const float4 v = *(const float4*)&sol[(size_t)n * 9216 + p * 4];
    float* d = &sy[k * 676 + (ppy + 1) * 26 + ppx + 1];
    d[0] = v.x * A + B; d[1] = v.y * A + B;
    d[2] = v.z * A + B; d[3] = v.w * A + B;
  }
  __syncthreads();
  const int py = tid / 24, px = tid - py * 24;
  const int hb0 = py * 26 + px;
  float a = bias[co];
#pragma unroll 4
  for (int k = 0; k < 16; ++k) {
    const float* wp = w + (co * 16 + k) * 9;
    const float* sp = &sy[k * 676 + hb0];
#pragma unroll
    for (int dy = 0; dy < 3; ++dy)
#pragma unroll
      for (int dx = 0; dx < 3; ++dx)
        a += sp[dy * 26 + dx] * wp[dy * 3 + dx];
  }
  out[(size_t)(n * 128 + co) * 576 + tid] = a;
}

// ---------------------------------------------------------------------------
extern "C" void kernel_launch(void* const* d_in, const int* in_sizes, int n_in,
                              void* d_out, int out_size, void* d_ws, size_t ws_size,
                              hipStream_t stream) {
  const float* x       = (const float*)d_in[0];
  const float* grad_w1 = (const float*)d_in[2];
  const float* grad_b1 = (const float*)d_in[3];
  const float* grad_w2 = (const float*)d_in[4];
  const float* grad_b2 = (const float*)d_in[5];
  const float* att_w1  = (const float*)d_in[6];
  const float* att_b1  = (const float*)d_in[7];
  const float* att_w2  = (const float*)d_in[8];
  const float* att_b2  = (const float*)d_in[9];
  const float* se_w1   = (const float*)d_in[10];
  const float* se_b1   = (const float*)d_in[11];
  const float* se_w2   = (const float*)d_in[12];
  const float* se_b2   = (const float*)d_in[13];
  const float* gn_w    = (const float*)d_in[14];
  const float* gn_b    = (const float*)d_in[15];
  const float* post_w  = (const float*)d_in[16];
  const float* post_b  = (const float*)d_in[17];
  float* out = (float*)d_out;

  float* ws  = (float*)d_ws;
  float* t1a = ws;              // 147456
  float* t1g = t1a + 147456;    // 147456
  float* att = t1g + 147456;    // 147456
  float* grd = att + 147456;    // 147456
  float* sev = grd + 147456;    // 64
  float* sol = sev + 64;        // 36864
  double* acc = (double*)(sol + 36864);  // 8 doubles

  (void)hipFuncSetAttribute((const void*)chol_kernel,
                            hipFuncAttributeMaxDynamicSharedMemorySize,
                            (int)CHOL_LDS_BYTES);

  conv1se_kernel<<<dim3(65, 4), 576, 0, stream>>>(
      x, att_w1, att_b1, grad_w1, grad_b1,
      se_w1, se_b1, se_w2, se_b2, t1a, t1g, sev, acc);
  conv2_kernel<<<dim3(64, 4, 2), 576, 0, stream>>>(t1a, t1g, att_w2, att_b2,
                                                   grad_w2, grad_b2, att, grd);
  chol_kernel<<<64, CTH, CHOL_LDS_BYTES, stream>>>(att, grd, sol, acc);
  postgn_kernel<<<dim3(128, 4), 576, 0, stream>>>(sol, acc, sev, gn_w, gn_b,
                                                  post_w, post_b, out);
}